// Round 11
// baseline (566.883 us; speedup 1.0000x reference)
//
#include <hip/hip_runtime.h>
#include <hip/hip_bf16.h>

typedef __attribute__((ext_vector_type(8))) short s16x8;
typedef __attribute__((ext_vector_type(4))) float f32x4;
typedef unsigned short u16;
typedef unsigned int u32;

#define NB 16
#define NK 256
#define APP 768
#define DKK 96
#define NR 8
#define QSCALE 0.10206207261596575f   // 1/sqrt(96), folded into Q at projection

// MEASUREMENT ROUND: byte-exact R7 kernels (best known-good, 137.4us), with
// internal work replication so each dispatch exceeds the ~230us harness fills
// and surfaces in rocprof top-5 WITH counters: fused x3 (bid = blockIdx.x %
// 8768), attn x24 (bx = blockIdx.x & 3). Duplicate blocks write identical
// values -> deterministic. conv unchanged.

__device__ __forceinline__ u16 f2bf(float f) {
  union { float f; unsigned int u; } v; v.f = f;
  unsigned int x = v.u;
  x += 0x7fffu + ((x >> 16) & 1u);
  return (u16)(x >> 16);
}
__device__ __forceinline__ float bf2f(u16 h) {
  union { unsigned int u; float f; } v; v.u = ((unsigned int)h) << 16;
  return v.f;
}
__device__ __forceinline__ u32 cvtpk(float lo, float hi) {
  u32 r;
  asm("v_cvt_pk_bf16_f32 %0, %1, %2" : "=v"(r) : "v"(lo), "v"(hi));
  return r;
}
__device__ __forceinline__ float bflo(u32 pk) {   // float of low bf16
  union { u32 u; float f; } v; v.u = pk << 16; return v.f;
}
__device__ __forceinline__ float bfhi(u32 pk) {   // float of high bf16
  union { u32 u; float f; } v; v.u = pk & 0xffff0000u; return v.f;
}
__device__ __forceinline__ void gload_lds16(const void* g, void* l) {
  __builtin_amdgcn_global_load_lds(
      (const __attribute__((address_space(1))) unsigned int*)g,
      (__attribute__((address_space(3))) unsigned int*)l, 16, 0, 0);
}

// ---------------------------------------------------------------------------
// Kernel 0: convert f_a and the 3 projection weights to bf16.
// ---------------------------------------------------------------------------
__global__ __launch_bounds__(256) void conv_kernel(
    const float* __restrict__ fa,
    const float* __restrict__ WKw, const float* __restrict__ WQw,
    const float* __restrict__ WVw,
    u16* __restrict__ fab, u16* __restrict__ Wb)
{
  const int idx = blockIdx.x * 256 + threadIdx.x;
  const int faCh = NB * NK * APP / 8;      // 393216
  const int wCh  = NR * DKK * APP / 8;     // 73728 per weight array
  const float* src; u16* dst;
  if (idx < faCh) {
    src = fa + (size_t)idx * 8;
    dst = fab + (size_t)idx * 8;
  } else {
    int o = idx - faCh;
    int a = o / wCh;
    int oo = o - a * wCh;
    const float* wsrc = a == 0 ? WKw : (a == 1 ? WQw : WVw);
    src = wsrc + (size_t)oo * 8;
    dst = Wb + (size_t)a * (NR * DKK * APP) + (size_t)oo * 8;
  }
  float4 v0 = *(const float4*)src;
  float4 v1 = *(const float4*)(src + 4);
  s16x8 ov = {(short)f2bf(v0.x),(short)f2bf(v0.y),(short)f2bf(v0.z),(short)f2bf(v0.w),
              (short)f2bf(v1.x),(short)f2bf(v1.y),(short)f2bf(v1.z),(short)f2bf(v1.w)};
  *(s16x8*)dst = ov;
}

// ---------------------------------------------------------------------------
// Kernel 1 (FUSED proj + wg): R7 structure, 1:15 interleave; x3 replicated.
// ---------------------------------------------------------------------------
#define PROJ_BLKS 576
#define WG_BLKS 8192
#define FUSED_TOT (PROJ_BLKS + WG_BLKS)
#define FUSED_REP 3

__global__ __launch_bounds__(256) void fused_kernel(
    const u16* __restrict__ fab, const u16* __restrict__ Wb,
    const float* __restrict__ WKb, const float* __restrict__ WQb,
    const float* __restrict__ WVb,
    u16* __restrict__ wkF, u16* __restrict__ wqF, u16* __restrict__ wvF,
    const float* __restrict__ pos,
    const float* __restrict__ WGw, const float* __restrict__ WGb,
    u16* __restrict__ lb2)
{
  __shared__ u16 SH[26624];              // 53.2 KB, aliased by both paths
  const int t = threadIdx.x;
  const int lane = t & 63, w = t >> 6;
  const int c = lane & 15, g = lane >> 4;
  const int bid = blockIdx.x % FUSED_TOT;          // x3 replication
  const int q = bid / 15, rph = bid - q * 15;

  if (rph == 0 && q < PROJ_BLKS) {
    // ----------------------- proj path -----------------------
    u16* As = SH;                        // 8192 elems
    u16* Bs = SH + 8192;
    const int pb = q;
    const int wr = w >> 1, wc = w & 1;
    const int m0 = (pb & 31) * 128;
    const int ct = pb >> 5;              // 0..17
    const int c0 = ct * 128;

    f32x4 acc[4][4] = {};

    for (int k0 = 0; k0 < APP; k0 += 64) {
      __syncthreads();
      #pragma unroll
      for (int i = 0; i < 4; ++i) {
        int n = t + i * 256;             // chunk id, 0..1023
        int row = n >> 3, cg = n & 7;
        int scg = cg ^ (row & 7);        // pre-swizzled global col-group
        gload_lds16(fab + (size_t)(m0 + row) * APP + k0 + scg * 8, As + n * 8);
        gload_lds16(Wb  + (size_t)(c0 + row) * APP + k0 + scg * 8, Bs + n * 8);
      }
      __syncthreads();
      #pragma unroll
      for (int kc = 0; kc < 2; ++kc) {
        s16x8 af[4], bfr[4];
        #pragma unroll
        for (int i = 0; i < 4; ++i) {
          int arow = wr * 64 + i * 16 + c;
          af[i]  = *(const s16x8*)(As + (((arow << 3) | ((kc * 4 + g) ^ (arow & 7))) << 3));
          int brow = wc * 64 + i * 16 + c;
          bfr[i] = *(const s16x8*)(Bs + (((brow << 3) | ((kc * 4 + g) ^ (brow & 7))) << 3));
        }
        #pragma unroll
        for (int mi = 0; mi < 4; ++mi)
          #pragma unroll
          for (int ni = 0; ni < 4; ++ni)
            acc[mi][ni] = __builtin_amdgcn_mfma_f32_16x16x32_bf16(af[mi], bfr[ni], acc[mi][ni], 0, 0, 0);
      }
    }

    const int arr = ct / 6;              // 0=K 1=Q 2=V (tiles never straddle)
    const int cw0 = c0 - arr * APP;
    const float* bp = arr == 0 ? WKb : (arr == 1 ? WQb : WVb);

    #pragma unroll
    for (int mi = 0; mi < 4; ++mi)
      #pragma unroll
      for (int ni = 0; ni < 4; ++ni) {
        int clw = cw0 + wc * 64 + ni * 16 + c;    // 0..767
        float bias = bp[clw];
        int rr = clw / DKK, kk = clw - rr * DKK;  // r, k-within-head
        int mb = m0 + wr * 64 + mi * 16 + g * 4;  // 4 consecutive m
        int bi = mb >> 8, tt = mb & 255;
        size_t hb = (size_t)rr * NB + bi;
        if (arr == 2) {
          ushort4 pk4;
          pk4.x = f2bf(acc[mi][ni][0] + bias);
          pk4.y = f2bf(acc[mi][ni][1] + bias);
          pk4.z = f2bf(acc[mi][ni][2] + bias);
          pk4.w = f2bf(acc[mi][ni][3] + bias);
          *(ushort4*)&wvF[((hb * 32 + (tt >> 3)) * DKK + kk) * 8 + (tt & 7)] = pk4;
        } else {
          u16* op = arr == 0 ? wkF : wqF;
          size_t base = ((hb * 12 + (kk >> 3)) * NK) * 8 + (size_t)(kk & 7);
          #pragma unroll
          for (int e = 0; e < 4; ++e) {
            float val = acc[mi][ni][e] + bias;
            if (arr == 1) val *= QSCALE;
            op[base + (size_t)(tt + e) * 8] = f2bf(val);
          }
        }
      }
  } else {
    // ----------------------- wg path -----------------------
    const int nbefore = (q >= PROJ_BLKS) ? PROJ_BLKS : (q + (rph > 0 ? 1 : 0));
    const int wgid = bid - nbefore;      // 0..8191
    u16* Th = SH;                        // hi plane, 13312 elems (rows 96->104)
    u16* Tl = SH + 13312;                // lo plane
    const size_t row0 = (size_t)wgid * 128;

    // B-frags (hi/lo): lane (c,g) holds W[c&7][kc*32+g*8 .. +8]
    s16x8 bwh[3], bwl[3];
    #pragma unroll
    for (int kc = 0; kc < 3; ++kc) {
      const float* wp = WGw + (c & 7) * DKK + kc * 32 + g * 8;
      s16x8 hv, lv;
      #pragma unroll
      for (int j = 0; j < 4; ++j) {
        float x0 = wp[2 * j], x1 = wp[2 * j + 1];
        u32 h = cvtpk(x0, x1);
        u32 l = cvtpk(x0 - bflo(h), x1 - bfhi(h));
        hv[2 * j] = (short)(h & 0xffff); hv[2 * j + 1] = (short)(h >> 16);
        lv[2 * j] = (short)(l & 0xffff); lv[2 * j + 1] = (short)(l >> 16);
      }
      bwh[kc] = hv; bwl[kc] = lv;
    }
    const float bias = WGb[c & 7];

    // stage: 1536 chunks of 8 floats; dense, fully coalesced f32x4 loads
    #pragma unroll
    for (int i = 0; i < 6; ++i) {
      int qq = t + i * 256;
      int row = qq / 12, col8 = qq - row * 12;
      const float* s = pos + row0 * DKK + (size_t)qq * 8;
      float4 a = *(const float4*)s;
      float4 b = *(const float4*)(s + 4);
      uint4 ph, pl;
      ph.x = cvtpk(a.x, a.y); pl.x = cvtpk(a.x - bflo(ph.x), a.y - bfhi(ph.x));
      ph.y = cvtpk(a.z, a.w); pl.y = cvtpk(a.z - bflo(ph.y), a.w - bfhi(ph.y));
      ph.z = cvtpk(b.x, b.y); pl.z = cvtpk(b.x - bflo(ph.z), b.y - bfhi(ph.z));
      ph.w = cvtpk(b.z, b.w); pl.w = cvtpk(b.z - bflo(ph.w), b.w - bfhi(ph.w));
      *(uint4*)&Th[row * 104 + col8 * 8] = ph;
      *(uint4*)&Tl[row * 104 + col8 * 8] = pl;
    }
    __syncthreads();

    // compute: wave w -> local rows w*32 .. w*32+31, two 16-row groups
    #pragma unroll
    for (int gi = 0; gi < 2; ++gi) {
      int rowl = w * 32 + gi * 16;
      f32x4 acc = {0.f, 0.f, 0.f, 0.f};
      #pragma unroll
      for (int kc = 0; kc < 3; ++kc) {
        s16x8 ah = *(const s16x8*)&Th[(rowl + c) * 104 + kc * 32 + g * 8];
        s16x8 al = *(const s16x8*)&Tl[(rowl + c) * 104 + kc * 32 + g * 8];
        acc = __builtin_amdgcn_mfma_f32_16x16x32_bf16(ah, bwh[kc], acc, 0, 0, 0);
        acc = __builtin_amdgcn_mfma_f32_16x16x32_bf16(ah, bwl[kc], acc, 0, 0, 0);
        acc = __builtin_amdgcn_mfma_f32_16x16x32_bf16(al, bwh[kc], acc, 0, 0, 0);
      }
      if (c < 8) {
        size_t base = (size_t)c * (NB * NK * NK) + row0 + rowl + g * 4;
        float v0 = __logf(fmaxf(acc[0] + bias, 1e-6f));
        float v1 = __logf(fmaxf(acc[1] + bias, 1e-6f));
        float v2 = __logf(fmaxf(acc[2] + bias, 1e-6f));
        float v3 = __logf(fmaxf(acc[3] + bias, 1e-6f));
        uint2 pk;
        pk.x = cvtpk(v0, v1);
        pk.y = cvtpk(v2, v3);
        *(uint2*)(lb2 + base) = pk;      // 8B packed store
      }
    }
  }
}

// ---------------------------------------------------------------------------
// Kernel 2: attention (R7 config), x24 replicated via blockIdx.x & 3.
// ---------------------------------------------------------------------------
#define ATTN_REP 24

__global__ __launch_bounds__(256) void attn_kernel(
    const u16* __restrict__ wkF, const u16* __restrict__ wqF,
    const u16* __restrict__ wvF, const u16* __restrict__ lb2,
    const float* __restrict__ fa, float* __restrict__ out)
{
  __shared__ u16 Ps[4][16][40];   // per-wave P chunk [16 n][32 m]
  const int t = threadIdx.x;
  const int w = t >> 6, lane = t & 63;
  const int c = lane & 15, g = lane >> 4;
  const int b = blockIdx.y, r = blockIdx.z;
  const int nb = (blockIdx.x & 3) * 64 + w * 16;   // x24 replication

  const size_t hb = (size_t)r * NB + b;
  const u16* Qb = wqF + hb * (12 * NK * 8);
  const u16* Kb = wkF + hb * (12 * NK * 8);
  const u16* Vb = wvF + hb * (32 * DKK * 8);
  const u16* Br = lb2 + hb * NK * NK + (size_t)c * NK + nb + g * 4;

  s16x8 qf[3];
  #pragma unroll
  for (int kc = 0; kc < 3; ++kc)
    qf[kc] = *(const s16x8*)(Qb + ((kc * 4 + g) * NK + nb + c) * 8);

  // preload all 16 bias quads
  ushort4 bbr[16];
  #pragma unroll
  for (int mt = 0; mt < 16; ++mt)
    bbr[mt] = *(const ushort4*)(Br + (size_t)mt * 16 * NK);

  // S[n = nb+g*4+e][m = mt*16+c]
  f32x4 S[16];
  #pragma unroll
  for (int mt = 0; mt < 16; ++mt) {
    f32x4 sa = {bf2f(bbr[mt].x), bf2f(bbr[mt].y), bf2f(bbr[mt].z), bf2f(bbr[mt].w)};
    #pragma unroll
    for (int kc = 0; kc < 3; ++kc) {
      s16x8 kf = *(const s16x8*)(Kb + ((kc * 4 + g) * NK + mt * 16 + c) * 8);
      sa = __builtin_amdgcn_mfma_f32_16x16x32_bf16(qf[kc], kf, sa, 0, 0, 0);
    }
    S[mt] = sa;
  }

  // softmax over m: 16 in-lane + shfl_xor over the 16 c-lanes
  float rinv[4];
  #pragma unroll
  for (int e = 0; e < 4; ++e) {
    float mx = S[0][e];
    #pragma unroll
    for (int mt = 1; mt < 16; ++mt) mx = fmaxf(mx, S[mt][e]);
    mx = fmaxf(mx, __shfl_xor(mx, 1));
    mx = fmaxf(mx, __shfl_xor(mx, 2));
    mx = fmaxf(mx, __shfl_xor(mx, 4));
    mx = fmaxf(mx, __shfl_xor(mx, 8));
    float sm = 0.f;
    #pragma unroll
    for (int mt = 0; mt < 16; ++mt) {
      float p = __expf(S[mt][e] - mx);
      S[mt][e] = p;
      sm += p;
    }
    sm += __shfl_xor(sm, 1);
    sm += __shfl_xor(sm, 2);
    sm += __shfl_xor(sm, 4);
    sm += __shfl_xor(sm, 8);
    rinv[e] = 1.f / sm;
  }

  // PV in 8 chunks of 32 m
  f32x4 o[6];
  #pragma unroll
  for (int ki = 0; ki < 6; ++ki) o[ki] = (f32x4){0.f, 0.f, 0.f, 0.f};

  #pragma unroll
  for (int mc = 0; mc < 8; ++mc) {
    #pragma unroll
    for (int e = 0; e < 4; ++e) {
      Ps[w][g * 4 + e][c]      = f2bf(S[2 * mc][e]);
      Ps[w][g * 4 + e][16 + c] = f2bf(S[2 * mc + 1][e]);
    }
    s16x8 pa = *(const s16x8*)&Ps[w][c][g * 8];
    #pragma unroll
    for (int ki = 0; ki < 6; ++ki) {
      s16x8 vf = *(const s16x8*)(Vb + ((mc * 4 + g) * DKK + ki * 16 + c) * 8);
      o[ki] = __builtin_amdgcn_mfma_f32_16x16x32_bf16(pa, vf, o[ki], 0, 0, 0);
    }
  }

  // epilogue: normalize, residual, fp32 store
  #pragma unroll
  for (int ki = 0; ki < 6; ++ki)
    #pragma unroll
    for (int e = 0; e < 4; ++e) {
      int n = nb + g * 4 + e;
      size_t adr = ((size_t)b * NK + n) * (NR * DKK) + r * DKK + ki * 16 + c;
      out[adr] = o[ki][e] * rinv[e] + fa[adr];
    }
}

extern "C" void kernel_launch(void* const* d_in, const int* in_sizes, int n_in,
                              void* d_out, int out_size, void* d_ws, size_t ws_size,
                              hipStream_t stream) {
  (void)in_sizes; (void)n_in; (void)out_size; (void)ws_size;
  const float* fa  = (const float*)d_in[0];
  const float* pos = (const float*)d_in[1];
  const float* WGw = (const float*)d_in[2];
  const float* WGb = (const float*)d_in[3];
  const float* WKw = (const float*)d_in[4];
  const float* WKb = (const float*)d_in[5];
  const float* WQw = (const float*)d_in[6];
  const float* WQb = (const float*)d_in[7];
  const float* WVw = (const float*)d_in[8];
  const float* WVb = (const float*)d_in[9];
  float* outp = (float*)d_out;

  const size_t faN = (size_t)NB * NK * APP;       // 3,145,728
  const size_t wN  = (size_t)3 * NR * DKK * APP;  // 1,769,472
  const size_t kqv = (size_t)NR * NB * NK * DKK;  // 3,145,728 (all 3 layouts)
  u16* fab = (u16*)d_ws;
  u16* Wb  = fab + faN;
  u16* wkF = Wb + wN;
  u16* wqF = wkF + kqv;
  u16* wvF = wqF + kqv;
  u16* lb2 = wvF + kqv;

  hipLaunchKernelGGL(conv_kernel, dim3(2400), dim3(256), 0, stream,
                     fa, WKw, WQw, WVw, fab, Wb);
  hipLaunchKernelGGL(fused_kernel, dim3(FUSED_TOT * FUSED_REP), dim3(256), 0, stream,
                     fab, Wb, WKb, WQb, WVb, wkF, wqF, wvF, pos, WGw, WGb, lb2);
  hipLaunchKernelGGL(attn_kernel, dim3(4 * ATTN_REP, NB, NR), dim3(256), 0, stream,
                     wkF, wqF, wvF, lb2, fa, outp);
}

// Round 12
// 161.113 us; speedup vs baseline: 3.5186x; 3.5186x over previous
//
#include <hip/hip_runtime.h>
#include <hip/hip_bf16.h>

typedef __attribute__((ext_vector_type(8))) short s16x8;
typedef __attribute__((ext_vector_type(4))) float f32x4;
typedef unsigned short u16;
typedef unsigned int u32;

#define NB 16
#define NK 256
#define APP 768
#define DKK 96
#define NR 8
#define QSCALE 0.10206207261596575f   // 1/sqrt(96), folded into Q at projection

__device__ __forceinline__ u16 f2bf(float f) {
  union { float f; unsigned int u; } v; v.f = f;
  unsigned int x = v.u;
  x += 0x7fffu + ((x >> 16) & 1u);
  return (u16)(x >> 16);
}
__device__ __forceinline__ float bf2f(u16 h) {
  union { unsigned int u; float f; } v; v.u = ((unsigned int)h) << 16;
  return v.f;
}
__device__ __forceinline__ u32 cvtpk(float lo, float hi) {
  u32 r;
  asm("v_cvt_pk_bf16_f32 %0, %1, %2" : "=v"(r) : "v"(lo), "v"(hi));
  return r;
}
__device__ __forceinline__ float bflo(u32 pk) {   // float of low bf16
  union { u32 u; float f; } v; v.u = pk << 16; return v.f;
}
__device__ __forceinline__ float bfhi(u32 pk) {   // float of high bf16
  union { u32 u; float f; } v; v.u = pk & 0xffff0000u; return v.f;
}
__device__ __forceinline__ void gload_lds16(const void* g, void* l) {
  __builtin_amdgcn_global_load_lds(
      (const __attribute__((address_space(1))) unsigned int*)g,
      (__attribute__((address_space(3))) unsigned int*)l, 16, 0, 0);
}

// ---------------------------------------------------------------------------
// Kernel 0: convert f_a and the 3 projection weights to bf16.
// ---------------------------------------------------------------------------
__global__ __launch_bounds__(256) void conv_kernel(
    const float* __restrict__ fa,
    const float* __restrict__ WKw, const float* __restrict__ WQw,
    const float* __restrict__ WVw,
    u16* __restrict__ fab, u16* __restrict__ Wb)
{
  const int idx = blockIdx.x * 256 + threadIdx.x;
  const int faCh = NB * NK * APP / 8;      // 393216
  const int wCh  = NR * DKK * APP / 8;     // 73728 per weight array
  const float* src; u16* dst;
  if (idx < faCh) {
    src = fa + (size_t)idx * 8;
    dst = fab + (size_t)idx * 8;
  } else {
    int o = idx - faCh;
    int a = o / wCh;
    int oo = o - a * wCh;
    const float* wsrc = a == 0 ? WKw : (a == 1 ? WQw : WVw);
    src = wsrc + (size_t)oo * 8;
    dst = Wb + (size_t)a * (NR * DKK * APP) + (size_t)oo * 8;
  }
  float4 v0 = *(const float4*)src;
  float4 v1 = *(const float4*)(src + 4);
  s16x8 ov = {(short)f2bf(v0.x),(short)f2bf(v0.y),(short)f2bf(v0.z),(short)f2bf(v0.w),
              (short)f2bf(v1.x),(short)f2bf(v1.y),(short)f2bf(v1.z),(short)f2bf(v1.w)};
  *(s16x8*)dst = ov;
}

// ---------------------------------------------------------------------------
// Kernel 1 (FUSED proj + wg): R7 structure, but wg blocks now cover 64 rows
// (Th/Tl 26.6 KB <= proj's 32 KB) -> LDS no longer caps blocks/CU at 3;
// 16384 shorter wg blocks stagger staging/compute phases across the CU.
// R11 counters: hbm 28%, VALU 30%, Mfma 9%, Occ 21.6% -> latency/occupancy
// bound; this raises the occupancy ceiling 12 -> 16 waves/CU (VGPR-bound).
// proj path and all inner math byte-identical to R7 (known-good).
// ---------------------------------------------------------------------------
#define PROJ_BLKS 576
#define WG_BLKS 16384            // 64 rows each
#define GRP 29                   // 1 proj : 28 wg per group
#define NGRP_BLKS (PROJ_BLKS * GRP)   // 16704

__global__ __launch_bounds__(256) void fused_kernel(
    const u16* __restrict__ fab, const u16* __restrict__ Wb,
    const float* __restrict__ WKb, const float* __restrict__ WQb,
    const float* __restrict__ WVb,
    u16* __restrict__ wkF, u16* __restrict__ wqF, u16* __restrict__ wvF,
    const float* __restrict__ pos,
    const float* __restrict__ WGw, const float* __restrict__ WGb,
    u16* __restrict__ lb2)
{
  __shared__ u16 SH[16384];              // 32 KB, aliased by both paths
  const int t = threadIdx.x;
  const int lane = t & 63, w = t >> 6;
  const int c = lane & 15, g = lane >> 4;
  const int bid = blockIdx.x;

  int isProj, projId, wgid;
  if (bid < NGRP_BLKS) {
    int q = bid / GRP, rem = bid - q * GRP;
    isProj = (rem == 0);
    projId = q;
    wgid = q * (GRP - 1) + rem - 1;
  } else {
    isProj = 0;
    projId = 0;
    wgid = (NGRP_BLKS - PROJ_BLKS) + (bid - NGRP_BLKS);  // 16128 + tail
  }

  if (isProj) {
    // ----------------------- proj path -----------------------
    u16* As = SH;                        // 8192 elems
    u16* Bs = SH + 8192;
    const int pb = projId;
    const int wr = w >> 1, wc = w & 1;
    const int m0 = (pb & 31) * 128;
    const int ct = pb >> 5;              // 0..17
    const int c0 = ct * 128;

    f32x4 acc[4][4] = {};

    for (int k0 = 0; k0 < APP; k0 += 64) {
      __syncthreads();
      #pragma unroll
      for (int i = 0; i < 4; ++i) {
        int n = t + i * 256;             // chunk id, 0..1023
        int row = n >> 3, cg = n & 7;
        int scg = cg ^ (row & 7);        // pre-swizzled global col-group
        gload_lds16(fab + (size_t)(m0 + row) * APP + k0 + scg * 8, As + n * 8);
        gload_lds16(Wb  + (size_t)(c0 + row) * APP + k0 + scg * 8, Bs + n * 8);
      }
      __syncthreads();
      #pragma unroll
      for (int kc = 0; kc < 2; ++kc) {
        s16x8 af[4], bfr[4];
        #pragma unroll
        for (int i = 0; i < 4; ++i) {
          int arow = wr * 64 + i * 16 + c;
          af[i]  = *(const s16x8*)(As + (((arow << 3) | ((kc * 4 + g) ^ (arow & 7))) << 3));
          int brow = wc * 64 + i * 16 + c;
          bfr[i] = *(const s16x8*)(Bs + (((brow << 3) | ((kc * 4 + g) ^ (brow & 7))) << 3));
        }
        #pragma unroll
        for (int mi = 0; mi < 4; ++mi)
          #pragma unroll
          for (int ni = 0; ni < 4; ++ni)
            acc[mi][ni] = __builtin_amdgcn_mfma_f32_16x16x32_bf16(af[mi], bfr[ni], acc[mi][ni], 0, 0, 0);
      }
    }

    const int arr = ct / 6;              // 0=K 1=Q 2=V (tiles never straddle)
    const int cw0 = c0 - arr * APP;
    const float* bp = arr == 0 ? WKb : (arr == 1 ? WQb : WVb);

    #pragma unroll
    for (int mi = 0; mi < 4; ++mi)
      #pragma unroll
      for (int ni = 0; ni < 4; ++ni) {
        int clw = cw0 + wc * 64 + ni * 16 + c;    // 0..767
        float bias = bp[clw];
        int rr = clw / DKK, kk = clw - rr * DKK;  // r, k-within-head
        int mb = m0 + wr * 64 + mi * 16 + g * 4;  // 4 consecutive m
        int bi = mb >> 8, tt = mb & 255;
        size_t hb = (size_t)rr * NB + bi;
        if (arr == 2) {
          ushort4 pk4;
          pk4.x = f2bf(acc[mi][ni][0] + bias);
          pk4.y = f2bf(acc[mi][ni][1] + bias);
          pk4.z = f2bf(acc[mi][ni][2] + bias);
          pk4.w = f2bf(acc[mi][ni][3] + bias);
          *(ushort4*)&wvF[((hb * 32 + (tt >> 3)) * DKK + kk) * 8 + (tt & 7)] = pk4;
        } else {
          u16* op = arr == 0 ? wkF : wqF;
          size_t base = ((hb * 12 + (kk >> 3)) * NK) * 8 + (size_t)(kk & 7);
          #pragma unroll
          for (int e = 0; e < 4; ++e) {
            float val = acc[mi][ni][e] + bias;
            if (arr == 1) val *= QSCALE;
            op[base + (size_t)(tt + e) * 8] = f2bf(val);
          }
        }
      }
  } else {
    // -------------------- wg path (64 rows/block) --------------------
    u16* Th = SH;                        // hi plane [64][104] = 13312 B
    u16* Tl = SH + 6656;                 // lo plane
    const size_t row0 = (size_t)wgid * 64;

    // B-frags (hi/lo): lane (c,g) holds W[c&7][kc*32+g*8 .. +8]
    s16x8 bwh[3], bwl[3];
    #pragma unroll
    for (int kc = 0; kc < 3; ++kc) {
      const float* wp = WGw + (c & 7) * DKK + kc * 32 + g * 8;
      s16x8 hv, lv;
      #pragma unroll
      for (int j = 0; j < 4; ++j) {
        float x0 = wp[2 * j], x1 = wp[2 * j + 1];
        u32 h = cvtpk(x0, x1);
        u32 l = cvtpk(x0 - bflo(h), x1 - bfhi(h));
        hv[2 * j] = (short)(h & 0xffff); hv[2 * j + 1] = (short)(h >> 16);
        lv[2 * j] = (short)(l & 0xffff); lv[2 * j + 1] = (short)(l >> 16);
      }
      bwh[kc] = hv; bwl[kc] = lv;
    }
    const float bias = WGb[c & 7];

    // stage: 64 rows x 96 = 768 chunks of 8 floats; dense coalesced loads
    #pragma unroll
    for (int i = 0; i < 3; ++i) {
      int qq = t + i * 256;
      int row = qq / 12, col8 = qq - row * 12;
      const float* s = pos + row0 * DKK + (size_t)qq * 8;
      float4 a = *(const float4*)s;
      float4 b = *(const float4*)(s + 4);
      uint4 ph, pl;
      ph.x = cvtpk(a.x, a.y); pl.x = cvtpk(a.x - bflo(ph.x), a.y - bfhi(ph.x));
      ph.y = cvtpk(a.z, a.w); pl.y = cvtpk(a.z - bflo(ph.y), a.w - bfhi(ph.y));
      ph.z = cvtpk(b.x, b.y); pl.z = cvtpk(b.x - bflo(ph.z), b.y - bfhi(ph.z));
      ph.w = cvtpk(b.z, b.w); pl.w = cvtpk(b.z - bflo(ph.w), b.w - bfhi(ph.w));
      *(uint4*)&Th[row * 104 + col8 * 8] = ph;
      *(uint4*)&Tl[row * 104 + col8 * 8] = pl;
    }
    __syncthreads();

    // compute: wave w -> local rows w*16 .. w*16+15 (one 16-row group)
    {
      int rowl = w * 16;
      f32x4 acc = {0.f, 0.f, 0.f, 0.f};
      #pragma unroll
      for (int kc = 0; kc < 3; ++kc) {
        s16x8 ah = *(const s16x8*)&Th[(rowl + c) * 104 + kc * 32 + g * 8];
        s16x8 al = *(const s16x8*)&Tl[(rowl + c) * 104 + kc * 32 + g * 8];
        acc = __builtin_amdgcn_mfma_f32_16x16x32_bf16(ah, bwh[kc], acc, 0, 0, 0);
        acc = __builtin_amdgcn_mfma_f32_16x16x32_bf16(ah, bwl[kc], acc, 0, 0, 0);
        acc = __builtin_amdgcn_mfma_f32_16x16x32_bf16(al, bwh[kc], acc, 0, 0, 0);
      }
      if (c < 8) {
        size_t base = (size_t)c * (NB * NK * NK) + row0 + rowl + g * 4;
        float v0 = __logf(fmaxf(acc[0] + bias, 1e-6f));
        float v1 = __logf(fmaxf(acc[1] + bias, 1e-6f));
        float v2 = __logf(fmaxf(acc[2] + bias, 1e-6f));
        float v3 = __logf(fmaxf(acc[3] + bias, 1e-6f));
        uint2 pk;
        pk.x = cvtpk(v0, v1);
        pk.y = cvtpk(v2, v3);
        *(uint2*)(lb2 + base) = pk;      // 8B packed store
      }
    }
  }
}

// ---------------------------------------------------------------------------
// Kernel 2: attention (R7 config: 512 blocks x 4 waves, wave owns 16 n-rows).
// ---------------------------------------------------------------------------
__global__ __launch_bounds__(256) void attn_kernel(
    const u16* __restrict__ wkF, const u16* __restrict__ wqF,
    const u16* __restrict__ wvF, const u16* __restrict__ lb2,
    const float* __restrict__ fa, float* __restrict__ out)
{
  __shared__ u16 Ps[4][16][40];   // per-wave P chunk [16 n][32 m]
  const int t = threadIdx.x;
  const int w = t >> 6, lane = t & 63;
  const int c = lane & 15, g = lane >> 4;
  const int b = blockIdx.y, r = blockIdx.z;
  const int nb = blockIdx.x * 64 + w * 16;

  const size_t hb = (size_t)r * NB + b;
  const u16* Qb = wqF + hb * (12 * NK * 8);
  const u16* Kb = wkF + hb * (12 * NK * 8);
  const u16* Vb = wvF + hb * (32 * DKK * 8);
  const u16* Br = lb2 + hb * NK * NK + (size_t)c * NK + nb + g * 4;

  s16x8 qf[3];
  #pragma unroll
  for (int kc = 0; kc < 3; ++kc)
    qf[kc] = *(const s16x8*)(Qb + ((kc * 4 + g) * NK + nb + c) * 8);

  // preload all 16 bias quads
  ushort4 bbr[16];
  #pragma unroll
  for (int mt = 0; mt < 16; ++mt)
    bbr[mt] = *(const ushort4*)(Br + (size_t)mt * 16 * NK);

  // S[n = nb+g*4+e][m = mt*16+c]
  f32x4 S[16];
  #pragma unroll
  for (int mt = 0; mt < 16; ++mt) {
    f32x4 sa = {bf2f(bbr[mt].x), bf2f(bbr[mt].y), bf2f(bbr[mt].z), bf2f(bbr[mt].w)};
    #pragma unroll
    for (int kc = 0; kc < 3; ++kc) {
      s16x8 kf = *(const s16x8*)(Kb + ((kc * 4 + g) * NK + mt * 16 + c) * 8);
      sa = __builtin_amdgcn_mfma_f32_16x16x32_bf16(qf[kc], kf, sa, 0, 0, 0);
    }
    S[mt] = sa;
  }

  // softmax over m: 16 in-lane + shfl_xor over the 16 c-lanes
  float rinv[4];
  #pragma unroll
  for (int e = 0; e < 4; ++e) {
    float mx = S[0][e];
    #pragma unroll
    for (int mt = 1; mt < 16; ++mt) mx = fmaxf(mx, S[mt][e]);
    mx = fmaxf(mx, __shfl_xor(mx, 1));
    mx = fmaxf(mx, __shfl_xor(mx, 2));
    mx = fmaxf(mx, __shfl_xor(mx, 4));
    mx = fmaxf(mx, __shfl_xor(mx, 8));
    float sm = 0.f;
    #pragma unroll
    for (int mt = 0; mt < 16; ++mt) {
      float p = __expf(S[mt][e] - mx);
      S[mt][e] = p;
      sm += p;
    }
    sm += __shfl_xor(sm, 1);
    sm += __shfl_xor(sm, 2);
    sm += __shfl_xor(sm, 4);
    sm += __shfl_xor(sm, 8);
    rinv[e] = 1.f / sm;
  }

  // PV in 8 chunks of 32 m
  f32x4 o[6];
  #pragma unroll
  for (int ki = 0; ki < 6; ++ki) o[ki] = (f32x4){0.f, 0.f, 0.f, 0.f};

  #pragma unroll
  for (int mc = 0; mc < 8; ++mc) {
    #pragma unroll
    for (int e = 0; e < 4; ++e) {
      Ps[w][g * 4 + e][c]      = f2bf(S[2 * mc][e]);
      Ps[w][g * 4 + e][16 + c] = f2bf(S[2 * mc + 1][e]);
    }
    s16x8 pa = *(const s16x8*)&Ps[w][c][g * 8];
    #pragma unroll
    for (int ki = 0; ki < 6; ++ki) {
      s16x8 vf = *(const s16x8*)(Vb + ((mc * 4 + g) * DKK + ki * 16 + c) * 8);
      o[ki] = __builtin_amdgcn_mfma_f32_16x16x32_bf16(pa, vf, o[ki], 0, 0, 0);
    }
  }

  // epilogue: normalize, residual, fp32 store
  #pragma unroll
  for (int ki = 0; ki < 6; ++ki)
    #pragma unroll
    for (int e = 0; e < 4; ++e) {
      int n = nb + g * 4 + e;
      size_t adr = ((size_t)b * NK + n) * (NR * DKK) + r * DKK + ki * 16 + c;
      out[adr] = o[ki][e] * rinv[e] + fa[adr];
    }
}

extern "C" void kernel_launch(void* const* d_in, const int* in_sizes, int n_in,
                              void* d_out, int out_size, void* d_ws, size_t ws_size,
                              hipStream_t stream) {
  (void)in_sizes; (void)n_in; (void)out_size; (void)ws_size;
  const float* fa  = (const float*)d_in[0];
  const float* pos = (const float*)d_in[1];
  const float* WGw = (const float*)d_in[2];
  const float* WGb = (const float*)d_in[3];
  const float* WKw = (const float*)d_in[4];
  const float* WKb = (const float*)d_in[5];
  const float* WQw = (const float*)d_in[6];
  const float* WQb = (const float*)d_in[7];
  const float* WVw = (const float*)d_in[8];
  const float* WVb = (const float*)d_in[9];
  float* outp = (float*)d_out;

  const size_t faN = (size_t)NB * NK * APP;       // 3,145,728
  const size_t wN  = (size_t)3 * NR * DKK * APP;  // 1,769,472
  const size_t kqv = (size_t)NR * NB * NK * DKK;  // 3,145,728 (all 3 layouts)
  u16* fab = (u16*)d_ws;
  u16* Wb  = fab + faN;
  u16* wkF = Wb + wN;
  u16* wqF = wkF + kqv;
  u16* wvF = wqF + kqv;
  u16* lb2 = wvF + kqv;

  hipLaunchKernelGGL(conv_kernel, dim3(2400), dim3(256), 0, stream,
                     fa, WKw, WQw, WVw, fab, Wb);
  hipLaunchKernelGGL(fused_kernel, dim3(PROJ_BLKS + WG_BLKS), dim3(256), 0, stream,
                     fab, Wb, WKb, WQb, WVb, wkF, wqF, wvF, pos, WGw, WGb, lb2);
  hipLaunchKernelGGL(attn_kernel, dim3(4, NB, NR), dim3(256), 0, stream,
                     wkF, wqF, wvF, lb2, fa, outp);
}

// Round 13
// 134.845 us; speedup vs baseline: 4.2040x; 1.1948x over previous
//
#include <hip/hip_runtime.h>
#include <hip/hip_bf16.h>

typedef __attribute__((ext_vector_type(8))) short s16x8;
typedef __attribute__((ext_vector_type(4))) float f32x4;
typedef unsigned short u16;
typedef unsigned int u32;

#define NB 16
#define NK 256
#define APP 768
#define DKK 96
#define NR 8
#define QSCALE 0.10206207261596575f   // 1/sqrt(96), folded into Q at projection

__device__ __forceinline__ u16 f2bf(float f) {
  union { float f; unsigned int u; } v; v.f = f;
  unsigned int x = v.u;
  x += 0x7fffu + ((x >> 16) & 1u);
  return (u16)(x >> 16);
}
__device__ __forceinline__ float bf2f(u16 h) {
  union { unsigned int u; float f; } v; v.u = ((unsigned int)h) << 16;
  return v.f;
}
__device__ __forceinline__ u32 cvtpk(float lo, float hi) {
  u32 r;
  asm("v_cvt_pk_bf16_f32 %0, %1, %2" : "=v"(r) : "v"(lo), "v"(hi));
  return r;
}
__device__ __forceinline__ float bflo(u32 pk) {   // float of low bf16
  union { u32 u; float f; } v; v.u = pk << 16; return v.f;
}
__device__ __forceinline__ float bfhi(u32 pk) {   // float of high bf16
  union { u32 u; float f; } v; v.u = pk & 0xffff0000u; return v.f;
}
__device__ __forceinline__ void gload_lds16(const void* g, void* l) {
  __builtin_amdgcn_global_load_lds(
      (const __attribute__((address_space(1))) unsigned int*)g,
      (__attribute__((address_space(3))) unsigned int*)l, 16, 0, 0);
}

// ---------------------------------------------------------------------------
// Kernel 0: convert f_a and the 3 projection weights to bf16.
// ---------------------------------------------------------------------------
__global__ __launch_bounds__(256) void conv_kernel(
    const float* __restrict__ fa,
    const float* __restrict__ WKw, const float* __restrict__ WQw,
    const float* __restrict__ WVw,
    u16* __restrict__ fab, u16* __restrict__ Wb)
{
  const int idx = blockIdx.x * 256 + threadIdx.x;
  const int faCh = NB * NK * APP / 8;      // 393216
  const int wCh  = NR * DKK * APP / 8;     // 73728 per weight array
  const float* src; u16* dst;
  if (idx < faCh) {
    src = fa + (size_t)idx * 8;
    dst = fab + (size_t)idx * 8;
  } else {
    int o = idx - faCh;
    int a = o / wCh;
    int oo = o - a * wCh;
    const float* wsrc = a == 0 ? WKw : (a == 1 ? WQw : WVw);
    src = wsrc + (size_t)oo * 8;
    dst = Wb + (size_t)a * (NR * DKK * APP) + (size_t)oo * 8;
  }
  float4 v0 = *(const float4*)src;
  float4 v1 = *(const float4*)(src + 4);
  s16x8 ov = {(short)f2bf(v0.x),(short)f2bf(v0.y),(short)f2bf(v0.z),(short)f2bf(v0.w),
              (short)f2bf(v1.x),(short)f2bf(v1.y),(short)f2bf(v1.z),(short)f2bf(v1.w)};
  *(s16x8*)dst = ov;
}

// ---------------------------------------------------------------------------
// Kernel 1 (FUSED proj + wg): 2880 blocks in groups of 5 (1 proj + 4 wg).
// proj: byte-identical to R7 (verified). wg: PERSISTENT blocks, grid-stride
// over 16384 tiles of 64 rows, LDS double-buffered (2 x 26.6 KB = 53.2 KB,
// same 3 blocks/CU as R7): per iter, issue tile k+1 loads EARLY, compute
// tile k from buf[cur] (MFMA+log+store hides the HBM latency), then cvt +
// ds_write tile k+1 into buf[cur^1], one barrier, swap.  R11 diagnosis:
// latency-bound (hbm 28%, VALU 30%, Mfma 9%, Occ 22%) -> keep loads in
// flight during compute; amortize B-frag setup over ~7 tiles.
// ---------------------------------------------------------------------------
#define PROJ_BLKS 576
#define WG_BLKS 2304
#define NTILES 16384             // 1048576 rows / 64

__global__ __launch_bounds__(256) void fused_kernel(
    const u16* __restrict__ fab, const u16* __restrict__ Wb,
    const float* __restrict__ WKb, const float* __restrict__ WQb,
    const float* __restrict__ WVb,
    u16* __restrict__ wkF, u16* __restrict__ wqF, u16* __restrict__ wvF,
    const float* __restrict__ pos,
    const float* __restrict__ WGw, const float* __restrict__ WGb,
    u16* __restrict__ lb2)
{
  __shared__ u16 SH[26624];              // 53.2 KB: proj 32 KB | wg 2x(hi+lo)
  const int t = threadIdx.x;
  const int lane = t & 63, w = t >> 6;
  const int c = lane & 15, g = lane >> 4;
  const int bid = blockIdx.x;
  const int q = bid / 5, rem = bid - q * 5;

  if (rem == 0) {
    // ----------------------- proj path (R7, verified) -----------------------
    u16* As = SH;                        // 8192 elems
    u16* Bs = SH + 8192;
    const int pb = q;                    // 0..575
    const int wr = w >> 1, wc = w & 1;
    const int m0 = (pb & 31) * 128;
    const int ct = pb >> 5;              // 0..17
    const int c0 = ct * 128;

    f32x4 acc[4][4] = {};

    for (int k0 = 0; k0 < APP; k0 += 64) {
      __syncthreads();
      #pragma unroll
      for (int i = 0; i < 4; ++i) {
        int n = t + i * 256;             // chunk id, 0..1023
        int row = n >> 3, cg = n & 7;
        int scg = cg ^ (row & 7);        // pre-swizzled global col-group
        gload_lds16(fab + (size_t)(m0 + row) * APP + k0 + scg * 8, As + n * 8);
        gload_lds16(Wb  + (size_t)(c0 + row) * APP + k0 + scg * 8, Bs + n * 8);
      }
      __syncthreads();
      #pragma unroll
      for (int kc = 0; kc < 2; ++kc) {
        s16x8 af[4], bfr[4];
        #pragma unroll
        for (int i = 0; i < 4; ++i) {
          int arow = wr * 64 + i * 16 + c;
          af[i]  = *(const s16x8*)(As + (((arow << 3) | ((kc * 4 + g) ^ (arow & 7))) << 3));
          int brow = wc * 64 + i * 16 + c;
          bfr[i] = *(const s16x8*)(Bs + (((brow << 3) | ((kc * 4 + g) ^ (brow & 7))) << 3));
        }
        #pragma unroll
        for (int mi = 0; mi < 4; ++mi)
          #pragma unroll
          for (int ni = 0; ni < 4; ++ni)
            acc[mi][ni] = __builtin_amdgcn_mfma_f32_16x16x32_bf16(af[mi], bfr[ni], acc[mi][ni], 0, 0, 0);
      }
    }

    const int arr = ct / 6;              // 0=K 1=Q 2=V (tiles never straddle)
    const int cw0 = c0 - arr * APP;
    const float* bp = arr == 0 ? WKb : (arr == 1 ? WQb : WVb);

    #pragma unroll
    for (int mi = 0; mi < 4; ++mi)
      #pragma unroll
      for (int ni = 0; ni < 4; ++ni) {
        int clw = cw0 + wc * 64 + ni * 16 + c;    // 0..767
        float bias = bp[clw];
        int rr = clw / DKK, kk = clw - rr * DKK;  // r, k-within-head
        int mb = m0 + wr * 64 + mi * 16 + g * 4;  // 4 consecutive m
        int bi = mb >> 8, tt = mb & 255;
        size_t hb = (size_t)rr * NB + bi;
        if (arr == 2) {
          ushort4 pk4;
          pk4.x = f2bf(acc[mi][ni][0] + bias);
          pk4.y = f2bf(acc[mi][ni][1] + bias);
          pk4.z = f2bf(acc[mi][ni][2] + bias);
          pk4.w = f2bf(acc[mi][ni][3] + bias);
          *(ushort4*)&wvF[((hb * 32 + (tt >> 3)) * DKK + kk) * 8 + (tt & 7)] = pk4;
        } else {
          u16* op = arr == 0 ? wkF : wqF;
          size_t base = ((hb * 12 + (kk >> 3)) * NK) * 8 + (size_t)(kk & 7);
          #pragma unroll
          for (int e = 0; e < 4; ++e) {
            float val = acc[mi][ni][e] + bias;
            if (arr == 1) val *= QSCALE;
            op[base + (size_t)(tt + e) * 8] = f2bf(val);
          }
        }
      }
  } else {
    // ---------- wg path: persistent, 64-row tiles, LDS double-buffer ----------
    const int wgid = q * 4 + rem - 1;    // 0..2303

    // B-frags (hi/lo): lane (c,g) holds W[c&7][kc*32+g*8 .. +8]
    s16x8 bwh[3], bwl[3];
    #pragma unroll
    for (int kc = 0; kc < 3; ++kc) {
      const float* wp = WGw + (c & 7) * DKK + kc * 32 + g * 8;
      s16x8 hv, lv;
      #pragma unroll
      for (int j = 0; j < 4; ++j) {
        float x0 = wp[2 * j], x1 = wp[2 * j + 1];
        u32 h = cvtpk(x0, x1);
        u32 l = cvtpk(x0 - bflo(h), x1 - bfhi(h));
        hv[2 * j] = (short)(h & 0xffff); hv[2 * j + 1] = (short)(h >> 16);
        lv[2 * j] = (short)(l & 0xffff); lv[2 * j + 1] = (short)(l >> 16);
      }
      bwh[kc] = hv; bwl[kc] = lv;
    }
    const float bias = WGb[c & 7];

    // per-thread chunk geometry (3 chunks of 8 elems per 64-row tile)
    const int qq0 = t, qq1 = t + 256, qq2 = t + 512;
    const int r0 = qq0 / 12, c8_0 = qq0 - r0 * 12;
    const int r1 = qq1 / 12, c8_1 = qq1 - r1 * 12;
    const int r2 = qq2 / 12, c8_2 = qq2 - r2 * 12;
    const int ld0 = r0 * 104 + c8_0 * 8;
    const int ld1 = r1 * 104 + c8_1 * 8;
    const int ld2 = r2 * 104 + c8_2 * 8;
    const int rowl = w * 16;             // this wave's rows within the tile

    float4 la0, lb0, la1, lb1, la2, lb2v;

    // prologue: load tile wgid, cvt, write buf0
    int tile = wgid;
    {
      const float* s0 = pos + (size_t)tile * 6144 + (size_t)qq0 * 8;
      const float* s1 = pos + (size_t)tile * 6144 + (size_t)qq1 * 8;
      const float* s2 = pos + (size_t)tile * 6144 + (size_t)qq2 * 8;
      la0 = *(const float4*)s0; lb0 = *(const float4*)(s0 + 4);
      la1 = *(const float4*)s1; lb1 = *(const float4*)(s1 + 4);
      la2 = *(const float4*)s2; lb2v = *(const float4*)(s2 + 4);
    }
    {
      u16* Th = SH;                      // buf0 hi
      u16* Tl = SH + 6656;               // buf0 lo
      #pragma unroll
      for (int i = 0; i < 3; ++i) {
        float4 a = i == 0 ? la0 : (i == 1 ? la1 : la2);
        float4 b = i == 0 ? lb0 : (i == 1 ? lb1 : lb2v);
        int off = i == 0 ? ld0 : (i == 1 ? ld1 : ld2);
        uint4 ph, pl;
        ph.x = cvtpk(a.x, a.y); pl.x = cvtpk(a.x - bflo(ph.x), a.y - bfhi(ph.x));
        ph.y = cvtpk(a.z, a.w); pl.y = cvtpk(a.z - bflo(ph.y), a.w - bfhi(ph.y));
        ph.z = cvtpk(b.x, b.y); pl.z = cvtpk(b.x - bflo(ph.z), b.y - bfhi(ph.z));
        ph.w = cvtpk(b.z, b.w); pl.w = cvtpk(b.z - bflo(ph.w), b.w - bfhi(ph.w));
        *(uint4*)&Th[off] = ph;
        *(uint4*)&Tl[off] = pl;
      }
    }
    __syncthreads();

    int cur = 0;
    while (true) {
      const int nxt = tile + WG_BLKS;
      const bool more = (nxt < NTILES);
      if (more) {                        // issue next tile's loads EARLY
        const float* s0 = pos + (size_t)nxt * 6144 + (size_t)qq0 * 8;
        const float* s1 = pos + (size_t)nxt * 6144 + (size_t)qq1 * 8;
        const float* s2 = pos + (size_t)nxt * 6144 + (size_t)qq2 * 8;
        la0 = *(const float4*)s0; lb0 = *(const float4*)(s0 + 4);
        la1 = *(const float4*)s1; lb1 = *(const float4*)(s1 + 4);
        la2 = *(const float4*)s2; lb2v = *(const float4*)(s2 + 4);
      }
      // compute current tile from buf[cur] (loads for nxt in flight)
      {
        const u16* Th = SH + (cur ? 13312 : 0);
        const u16* Tl = Th + 6656;
        f32x4 acc = {0.f, 0.f, 0.f, 0.f};
        #pragma unroll
        for (int kc = 0; kc < 3; ++kc) {
          s16x8 ah = *(const s16x8*)&Th[(rowl + c) * 104 + kc * 32 + g * 8];
          s16x8 al = *(const s16x8*)&Tl[(rowl + c) * 104 + kc * 32 + g * 8];
          acc = __builtin_amdgcn_mfma_f32_16x16x32_bf16(ah, bwh[kc], acc, 0, 0, 0);
          acc = __builtin_amdgcn_mfma_f32_16x16x32_bf16(ah, bwl[kc], acc, 0, 0, 0);
          acc = __builtin_amdgcn_mfma_f32_16x16x32_bf16(al, bwh[kc], acc, 0, 0, 0);
        }
        if (c < 8) {
          size_t base = (size_t)c * (NB * NK * NK) + (size_t)tile * 64 + rowl + g * 4;
          float v0 = __logf(fmaxf(acc[0] + bias, 1e-6f));
          float v1 = __logf(fmaxf(acc[1] + bias, 1e-6f));
          float v2 = __logf(fmaxf(acc[2] + bias, 1e-6f));
          float v3 = __logf(fmaxf(acc[3] + bias, 1e-6f));
          uint2 pk;
          pk.x = cvtpk(v0, v1);
          pk.y = cvtpk(v2, v3);
          *(uint2*)(lb2 + base) = pk;    // 8B packed store
        }
      }
      if (!more) break;
      // cvt + write next tile into buf[cur^1]
      {
        u16* Th = SH + (cur ? 0 : 13312);
        u16* Tl = Th + 6656;
        #pragma unroll
        for (int i = 0; i < 3; ++i) {
          float4 a = i == 0 ? la0 : (i == 1 ? la1 : la2);
          float4 b = i == 0 ? lb0 : (i == 1 ? lb1 : lb2v);
          int off = i == 0 ? ld0 : (i == 1 ? ld1 : ld2);
          uint4 ph, pl;
          ph.x = cvtpk(a.x, a.y); pl.x = cvtpk(a.x - bflo(ph.x), a.y - bfhi(ph.x));
          ph.y = cvtpk(a.z, a.w); pl.y = cvtpk(a.z - bflo(ph.y), a.w - bfhi(ph.y));
          ph.z = cvtpk(b.x, b.y); pl.z = cvtpk(b.x - bflo(ph.z), b.y - bfhi(ph.z));
          ph.w = cvtpk(b.z, b.w); pl.w = cvtpk(b.z - bflo(ph.w), b.w - bfhi(ph.w));
          *(uint4*)&Th[off] = ph;
          *(uint4*)&Tl[off] = pl;
        }
      }
      __syncthreads();
      cur ^= 1;
      tile = nxt;
    }
  }
}

// ---------------------------------------------------------------------------
// Kernel 2: attention (R7 config, verified <=9.5us: 512 blocks x 4 waves).
// ---------------------------------------------------------------------------
__global__ __launch_bounds__(256) void attn_kernel(
    const u16* __restrict__ wkF, const u16* __restrict__ wqF,
    const u16* __restrict__ wvF, const u16* __restrict__ lb2,
    const float* __restrict__ fa, float* __restrict__ out)
{
  __shared__ u16 Ps[4][16][40];   // per-wave P chunk [16 n][32 m]
  const int t = threadIdx.x;
  const int w = t >> 6, lane = t & 63;
  const int c = lane & 15, g = lane >> 4;
  const int b = blockIdx.y, r = blockIdx.z;
  const int nb = blockIdx.x * 64 + w * 16;

  const size_t hb = (size_t)r * NB + b;
  const u16* Qb = wqF + hb * (12 * NK * 8);
  const u16* Kb = wkF + hb * (12 * NK * 8);
  const u16* Vb = wvF + hb * (32 * DKK * 8);
  const u16* Br = lb2 + hb * NK * NK + (size_t)c * NK + nb + g * 4;

  s16x8 qf[3];
  #pragma unroll
  for (int kc = 0; kc < 3; ++kc)
    qf[kc] = *(const s16x8*)(Qb + ((kc * 4 + g) * NK + nb + c) * 8);

  // preload all 16 bias quads
  ushort4 bbr[16];
  #pragma unroll
  for (int mt = 0; mt < 16; ++mt)
    bbr[mt] = *(const ushort4*)(Br + (size_t)mt * 16 * NK);

  // S[n = nb+g*4+e][m = mt*16+c]
  f32x4 S[16];
  #pragma unroll
  for (int mt = 0; mt < 16; ++mt) {
    f32x4 sa = {bf2f(bbr[mt].x), bf2f(bbr[mt].y), bf2f(bbr[mt].z), bf2f(bbr[mt].w)};
    #pragma unroll
    for (int kc = 0; kc < 3; ++kc) {
      s16x8 kf = *(const s16x8*)(Kb + ((kc * 4 + g) * NK + mt * 16 + c) * 8);
      sa = __builtin_amdgcn_mfma_f32_16x16x32_bf16(qf[kc], kf, sa, 0, 0, 0);
    }
    S[mt] = sa;
  }

  // softmax over m: 16 in-lane + shfl_xor over the 16 c-lanes
  float rinv[4];
  #pragma unroll
  for (int e = 0; e < 4; ++e) {
    float mx = S[0][e];
    #pragma unroll
    for (int mt = 1; mt < 16; ++mt) mx = fmaxf(mx, S[mt][e]);
    mx = fmaxf(mx, __shfl_xor(mx, 1));
    mx = fmaxf(mx, __shfl_xor(mx, 2));
    mx = fmaxf(mx, __shfl_xor(mx, 4));
    mx = fmaxf(mx, __shfl_xor(mx, 8));
    float sm = 0.f;
    #pragma unroll
    for (int mt = 0; mt < 16; ++mt) {
      float p = __expf(S[mt][e] - mx);
      S[mt][e] = p;
      sm += p;
    }
    sm += __shfl_xor(sm, 1);
    sm += __shfl_xor(sm, 2);
    sm += __shfl_xor(sm, 4);
    sm += __shfl_xor(sm, 8);
    rinv[e] = 1.f / sm;
  }

  // PV in 8 chunks of 32 m
  f32x4 o[6];
  #pragma unroll
  for (int ki = 0; ki < 6; ++ki) o[ki] = (f32x4){0.f, 0.f, 0.f, 0.f};

  #pragma unroll
  for (int mc = 0; mc < 8; ++mc) {
    #pragma unroll
    for (int e = 0; e < 4; ++e) {
      Ps[w][g * 4 + e][c]      = f2bf(S[2 * mc][e]);
      Ps[w][g * 4 + e][16 + c] = f2bf(S[2 * mc + 1][e]);
    }
    s16x8 pa = *(const s16x8*)&Ps[w][c][g * 8];
    #pragma unroll
    for (int ki = 0; ki < 6; ++ki) {
      s16x8 vf = *(const s16x8*)(Vb + ((mc * 4 + g) * DKK + ki * 16 + c) * 8);
      o[ki] = __builtin_amdgcn_mfma_f32_16x16x32_bf16(pa, vf, o[ki], 0, 0, 0);
    }
  }

  // epilogue: normalize, residual, fp32 store
  #pragma unroll
  for (int ki = 0; ki < 6; ++ki)
    #pragma unroll
    for (int e = 0; e < 4; ++e) {
      int n = nb + g * 4 + e;
      size_t adr = ((size_t)b * NK + n) * (NR * DKK) + r * DKK + ki * 16 + c;
      out[adr] = o[ki][e] * rinv[e] + fa[adr];
    }
}

extern "C" void kernel_launch(void* const* d_in, const int* in_sizes, int n_in,
                              void* d_out, int out_size, void* d_ws, size_t ws_size,
                              hipStream_t stream) {
  (void)in_sizes; (void)n_in; (void)out_size; (void)ws_size;
  const float* fa  = (const float*)d_in[0];
  const float* pos = (const float*)d_in[1];
  const float* WGw = (const float*)d_in[2];
  const float* WGb = (const float*)d_in[3];
  const float* WKw = (const float*)d_in[4];
  const float* WKb = (const float*)d_in[5];
  const float* WQw = (const float*)d_in[6];
  const float* WQb = (const float*)d_in[7];
  const float* WVw = (const float*)d_in[8];
  const float* WVb = (const float*)d_in[9];
  float* outp = (float*)d_out;

  const size_t faN = (size_t)NB * NK * APP;       // 3,145,728
  const size_t wN  = (size_t)3 * NR * DKK * APP;  // 1,769,472
  const size_t kqv = (size_t)NR * NB * NK * DKK;  // 3,145,728 (all 3 layouts)
  u16* fab = (u16*)d_ws;
  u16* Wb  = fab + faN;
  u16* wkF = Wb + wN;
  u16* wqF = wkF + kqv;
  u16* wvF = wqF + kqv;
  u16* lb2 = wvF + kqv;

  hipLaunchKernelGGL(conv_kernel, dim3(2400), dim3(256), 0, stream,
                     fa, WKw, WQw, WVw, fab, Wb);
  hipLaunchKernelGGL(fused_kernel, dim3((PROJ_BLKS + WG_BLKS) * 5 / 5 == 0 ? 2880 : 2880), dim3(256), 0, stream,
                     fab, Wb, WKb, WQb, WVb, wkF, wqF, wvF, pos, WGw, WGb, lb2);
  hipLaunchKernelGGL(attn_kernel, dim3(4, NB, NR), dim3(256), 0, stream,
                     wkF, wqF, wvF, lb2, fa, outp);
}